// Round 1
// baseline (2351.486 us; speedup 1.0000x reference)
//
#include <hip/hip_runtime.h>

#define N_DIM 256
#define BATCH 64

// One block per batch element. Thread j owns column j.
// scipy rectangular_lsap (Crouse JV variant): Dijkstra-like shortest augmenting
// path with dual potentials u (rows), v (cols). All per-column work is
// parallel; argmin is a wave-shuffle reduction + 4-wave LDS combine; the
// augmentation walk is serial on thread 0 (path length << N on average).
__global__ __launch_bounds__(256) void lap_kernel(const float* __restrict__ Dm,
                                                  double* __restrict__ batch_sums) {
    const int b = blockIdx.x;
    const int j = threadIdx.x;
    const float* __restrict__ cost = Dm + (size_t)b * N_DIM * N_DIM;

    __shared__ double u[N_DIM];
    __shared__ double v[N_DIM];
    __shared__ double spc[N_DIM];     // shortestPathCosts
    __shared__ int    path[N_DIM];    // predecessor row for column j
    __shared__ int    row4col[N_DIM];
    __shared__ int    col4row[N_DIM];
    __shared__ int    SC[N_DIM];      // column scanned (removed from frontier)
    __shared__ double red_val[4];
    __shared__ int    red_idx[4];
    __shared__ int    s_cur;
    __shared__ int    s_sink;
    __shared__ double s_minVal;

    u[j] = 0.0;
    v[j] = 0.0;
    row4col[j] = -1;
    col4row[j] = -1;
    __syncthreads();

    for (int i = 0; i < N_DIM; ++i) {
        // reset per-augmentation state
        spc[j] = (double)INFINITY;
        SC[j] = 0;
        if (j == 0) { s_cur = i; s_sink = -1; s_minVal = 0.0; }
        __syncthreads();

        for (int step = 0; step < N_DIM; ++step) {
            const int cur = s_cur;
            const double minVal = s_minVal;
            double cand;
            if (!SC[j]) {
                const double r = minVal + (double)cost[cur * N_DIM + j] - u[cur] - v[j];
                if (r < spc[j]) { spc[j] = r; path[j] = cur; }
                cand = spc[j];
            } else {
                cand = (double)INFINITY;
            }

            // block argmin over (cand, j)
            double val = cand;
            int idx = j;
            #pragma unroll
            for (int off = 32; off > 0; off >>= 1) {
                const double oval = __shfl_down(val, off);
                const int    oidx = __shfl_down(idx, off);
                if (oval < val) { val = oval; idx = oidx; }
            }
            const int lane = j & 63;
            const int wave = j >> 6;
            if (lane == 0) { red_val[wave] = val; red_idx[wave] = idx; }
            __syncthreads();
            if (j == 0) {
                double bv = red_val[0]; int bi = red_idx[0];
                #pragma unroll
                for (int w = 1; w < 4; ++w) {
                    if (red_val[w] < bv) { bv = red_val[w]; bi = red_idx[w]; }
                }
                s_minVal = bv;
                SC[bi] = 1;
                const int r4 = row4col[bi];
                if (r4 == -1) s_sink = bi; else s_cur = r4;
            }
            __syncthreads();
            if (s_sink != -1) break;
        }

        // dual update (fully parallel; rows in the tree are exactly
        // row4col[j] for scanned j, each distinct)
        const double minVal = s_minVal;
        if (SC[j]) {
            const double dv = minVal - spc[j];
            v[j] -= dv;
            const int r = row4col[j];
            if (r >= 0) u[r] += dv;
        }
        if (j == 0) u[i] += minVal;
        __syncthreads();

        // augment alternating path (serial, short)
        if (j == 0 && s_sink >= 0) {
            int jj = s_sink;
            while (true) {
                const int ii = path[jj];
                row4col[jj] = ii;
                const int tmp = col4row[ii];
                col4row[ii] = jj;
                jj = tmp;
                if (ii == i) break;
            }
        }
        __syncthreads();
    }

    // gather matched cost for row j and block-reduce the sum
    int c = col4row[j];
    if (c < 0) c = 0;  // unreachable safety
    double s = (double)cost[j * N_DIM + c];
    #pragma unroll
    for (int off = 32; off > 0; off >>= 1) s += __shfl_down(s, off);
    const int lane = j & 63;
    const int wave = j >> 6;
    if (lane == 0) red_val[wave] = s;
    __syncthreads();
    if (j == 0) batch_sums[b] = red_val[0] + red_val[1] + red_val[2] + red_val[3];
}

__global__ void finalize_kernel(const double* __restrict__ batch_sums,
                                float* __restrict__ out) {
    const int t = threadIdx.x;  // 64 threads, one wave
    double s = batch_sums[t];
    #pragma unroll
    for (int off = 32; off > 0; off >>= 1) s += __shfl_down(s, off);
    if (t == 0) out[0] = (float)(s / (double)((long long)BATCH * N_DIM));
}

extern "C" void kernel_launch(void* const* d_in, const int* in_sizes, int n_in,
                              void* d_out, int out_size, void* d_ws, size_t ws_size,
                              hipStream_t stream) {
    const float* Dm = (const float*)d_in[0];
    float* out = (float*)d_out;
    double* sums = (double*)d_ws;  // 64 * 8 = 512 bytes

    lap_kernel<<<BATCH, 256, 0, stream>>>(Dm, sums);
    finalize_kernel<<<1, 64, 0, stream>>>(sums, out);
}

// Round 2
// 2239.033 us; speedup vs baseline: 1.0502x; 1.0502x over previous
//
#include <hip/hip_runtime.h>

#define N_DIM 256
#define BATCH 64
#define CPT 4   // columns per thread
#define BS 64   // one wave per block

// Monotone map f32 -> u32 so unsigned compare == float ascending compare.
__device__ __forceinline__ unsigned int fmap(float f) {
    unsigned int b = __float_as_uint(f);
    return (b & 0x80000000u) ? ~b : (b | 0x80000000u);
}
__device__ __forceinline__ float funmap(unsigned int m) {
    return __uint_as_float((m & 0x80000000u) ? (m ^ 0x80000000u) : ~m);
}

// One block = one wave = one batch element. Thread t owns columns 4t..4t+3.
// JV shortest-augmenting-path LAP. No barriers inside the Dijkstra loop:
// argmin is a 6-step shfl_xor butterfly on a packed (mapped_val<<8 | col) key;
// all lanes end up with the winner so no broadcast step is needed.
__global__ __launch_bounds__(BS) void lap_kernel(const float* __restrict__ Dm,
                                                 double* __restrict__ batch_sums) {
    const int b = blockIdx.x;
    const int t = threadIdx.x;  // 0..63
    const float* __restrict__ cost = Dm + (size_t)b * N_DIM * N_DIM;

    __shared__ float u[N_DIM];        // row duals (runtime-indexed)
    __shared__ int   row4col[N_DIM];  // runtime-indexed
    __shared__ int   col4row[N_DIM];  // runtime-indexed
    __shared__ int   path[N_DIM];     // predecessor row per column

    // register state for the 4 owned columns (static indexing only)
    float v[CPT];
    float spc[CPT];
    int   scanmask;

    #pragma unroll
    for (int k = 0; k < CPT; ++k) {
        const int col = t * CPT + k;
        u[col] = 0.0f;
        row4col[col] = -1;
        col4row[col] = -1;
        v[k] = 0.0f;
    }
    __syncthreads();

    for (int i = 0; i < N_DIM; ++i) {
        #pragma unroll
        for (int k = 0; k < CPT; ++k) spc[k] = INFINITY;
        scanmask = 0;
        int   cur = i;
        float minVal = 0.0f;
        int   sink = -1;

        while (true) {
            // one float4 load = this thread's 4 contiguous columns of row `cur`
            const float4 c4 = ((const float4*)(cost + (size_t)cur * N_DIM))[t];
            const float ucur = u[cur];  // broadcast LDS read
            const float cc[CPT] = {c4.x, c4.y, c4.z, c4.w};

            unsigned long long key = ~0ull;
            #pragma unroll
            for (int k = 0; k < CPT; ++k) {
                if (!(scanmask & (1 << k))) {
                    const int col = t * CPT + k;
                    const float r = minVal + cc[k] - ucur - v[k];
                    if (r < spc[k]) { spc[k] = r; path[col] = cur; }
                    const unsigned long long kk =
                        ((unsigned long long)fmap(spc[k]) << 8) | (unsigned)col;
                    if (kk < key) key = kk;
                }
            }

            // 64-lane butterfly min — every lane gets the global winner
            #pragma unroll
            for (int off = 32; off > 0; off >>= 1) {
                const unsigned long long o = __shfl_xor(key, off);
                if (o < key) key = o;
            }

            const int bi = (int)(key & 0xFFu);
            minVal = funmap((unsigned int)(key >> 8));
            if ((bi >> 2) == t) scanmask |= 1 << (bi & 3);  // owner marks scanned
            const int r4 = row4col[bi];  // broadcast LDS read
            if (r4 < 0) { sink = bi; break; }
            cur = r4;
        }

        // dual update (parallel; matched rows of scanned cols are distinct)
        #pragma unroll
        for (int k = 0; k < CPT; ++k) {
            if (scanmask & (1 << k)) {
                const int col = t * CPT + k;
                const float dv = minVal - spc[k];
                v[k] -= dv;
                const int r = row4col[col];
                if (r >= 0) u[r] += dv;
            }
        }
        if (t == 0) u[i] += minVal;

        // augment alternating path (serial, short; DS ops in-order per wave so
        // the dual-update reads of row4col above are already issued)
        if (t == 0) {
            int jj = sink;
            while (true) {
                const int ii = path[jj];
                row4col[jj] = ii;
                const int tmp = col4row[ii];
                col4row[ii] = jj;
                jj = tmp;
                if (ii == i) break;
            }
        }
        __syncthreads();  // single-wave: cheap; orders u/row4col/col4row writes
    }

    // gather matched costs (4 rows per thread) and wave-reduce
    double s = 0.0;
    #pragma unroll
    for (int k = 0; k < CPT; ++k) {
        const int row = t * CPT + k;
        const int c = col4row[row];
        s += (double)cost[(size_t)row * N_DIM + c];
    }
    #pragma unroll
    for (int off = 32; off > 0; off >>= 1) s += __shfl_down(s, off);
    if (t == 0) batch_sums[b] = s;
}

__global__ void finalize_kernel(const double* __restrict__ batch_sums,
                                float* __restrict__ out) {
    const int t = threadIdx.x;  // 64 threads, one wave
    double s = batch_sums[t];
    #pragma unroll
    for (int off = 32; off > 0; off >>= 1) s += __shfl_down(s, off);
    if (t == 0) out[0] = (float)(s / (double)((long long)BATCH * N_DIM));
}

extern "C" void kernel_launch(void* const* d_in, const int* in_sizes, int n_in,
                              void* d_out, int out_size, void* d_ws, size_t ws_size,
                              hipStream_t stream) {
    const float* Dm = (const float*)d_in[0];
    float* out = (float*)d_out;
    double* sums = (double*)d_ws;  // 64 * 8 = 512 bytes

    lap_kernel<<<BATCH, BS, 0, stream>>>(Dm, sums);
    finalize_kernel<<<1, 64, 0, stream>>>(sums, out);
}

// Round 3
// 1479.953 us; speedup vs baseline: 1.5889x; 1.5129x over previous
//
#include <hip/hip_runtime.h>

#define N_DIM 256
#define BATCH 64
#define CPT 4   // columns per thread
#define BS 64   // one wave per block

// Full-wave (64-lane) f32 min via DPP: row_shr 1/2/4/8 then row_bcast15/31.
// Result valid in lane 63; broadcast via readlane. ~25cy vs ~200cy for
// ds_bpermute-based shfl_xor butterfly.
#define DPP_MIN_STEP(x, ctrl) do {                                            \
    int _s = __builtin_amdgcn_update_dpp(__float_as_int(x), __float_as_int(x),\
                                         (ctrl), 0xf, 0xf, false);            \
    (x) = fminf((x), __int_as_float(_s));                                     \
} while (0)

__device__ __forceinline__ float wave_min_f32(float x) {
    DPP_MIN_STEP(x, 0x111);  // row_shr:1
    DPP_MIN_STEP(x, 0x112);  // row_shr:2
    DPP_MIN_STEP(x, 0x114);  // row_shr:4
    DPP_MIN_STEP(x, 0x118);  // row_shr:8
    DPP_MIN_STEP(x, 0x142);  // row_bcast15
    DPP_MIN_STEP(x, 0x143);  // row_bcast31
    return __int_as_float(__builtin_amdgcn_readlane(__float_as_int(x), 63));
}

// One block = one wave = one batch element. Thread t owns columns 4t..4t+3.
// JV LAP: column-reduction greedy init, then shortest-augmenting-path for the
// remaining free rows. No barriers in the Dijkstra inner loop.
__global__ __launch_bounds__(BS) void lap_kernel(const float* __restrict__ Dm,
                                                 double* __restrict__ batch_sums) {
    const int b = blockIdx.x;
    const int t = threadIdx.x;  // 0..63
    const float* __restrict__ cost = Dm + (size_t)b * N_DIM * N_DIM;
    const float4* __restrict__ cost4 = (const float4*)cost;

    __shared__ float u[N_DIM];
    __shared__ int   row4col[N_DIM];
    __shared__ int   col4row[N_DIM];
    __shared__ int   path[N_DIM];
    __shared__ int   rowcand[N_DIM];

    float v[CPT];    // column duals (registers, static-indexed)
    float spc[CPT];  // shortest path costs
    int   scanmask;

    // ---- column reduction: v[j] = min_i cost[i][j], candidate row per col ----
    float colmin[CPT] = {INFINITY, INFINITY, INFINITY, INFINITY};
    int   colarg[CPT] = {0, 0, 0, 0};
    for (int r = 0; r < N_DIM; ++r) {
        const float4 c4 = cost4[r * BS + t];
        const float cc[CPT] = {c4.x, c4.y, c4.z, c4.w};
        #pragma unroll
        for (int k = 0; k < CPT; ++k) {
            if (cc[k] < colmin[k]) { colmin[k] = cc[k]; colarg[k] = r; }
        }
    }
    #pragma unroll
    for (int k = 0; k < CPT; ++k) {
        const int idx = t * CPT + k;
        u[idx] = 0.0f;
        row4col[idx] = -1;
        col4row[idx] = -1;
        rowcand[idx] = 0x7fffffff;
        v[k] = colmin[k];
    }
    __syncthreads();
    // greedy: each row goes to the lowest column that claims it (reduced cost 0)
    #pragma unroll
    for (int k = 0; k < CPT; ++k) atomicMin(&rowcand[colarg[k]], t * CPT + k);
    __syncthreads();
    #pragma unroll
    for (int k = 0; k < CPT; ++k) {
        const int col = t * CPT + k;
        if (rowcand[colarg[k]] == col) { row4col[col] = colarg[k]; col4row[colarg[k]] = col; }
    }
    __syncthreads();

    // ---- shortest augmenting path for each free row ----
    for (int i = 0; i < N_DIM; ++i) {
        if (col4row[i] >= 0) continue;  // uniform branch (LDS broadcast read)

        #pragma unroll
        for (int k = 0; k < CPT; ++k) spc[k] = INFINITY;
        scanmask = 0;
        int   cur = i;
        float minVal = 0.0f;
        int   sink = -1;

        for (int step = 0; step < N_DIM; ++step) {
            const float4 c4 = cost4[cur * BS + t];
            const float add = minVal - u[cur];  // lane-uniform
            const float cc[CPT] = {c4.x, c4.y, c4.z, c4.w};

            float candval = INFINITY;
            int   candcol = 0;
            #pragma unroll
            for (int k = 0; k < CPT; ++k) {
                if (!(scanmask & (1 << k))) {
                    const int col = t * CPT + k;
                    const float r = add + cc[k] - v[k];
                    if (r < spc[k]) { spc[k] = r; path[col] = cur; }
                    if (spc[k] < candval) { candval = spc[k]; candcol = col; }
                }
            }

            const float gmin = wave_min_f32(candval);
            const unsigned long long m = __ballot(candval == gmin);
            const int wl = __ffsll((long long)m) - 1;
            const int bi = __builtin_amdgcn_readlane(candcol, wl);

            minVal = gmin;
            if ((bi >> 2) == t) scanmask |= 1 << (bi & 3);
            const int r4 = row4col[bi];
            if (r4 < 0) { sink = bi; break; }
            cur = r4;
        }

        // dual update (parallel; matched rows of scanned cols are distinct)
        #pragma unroll
        for (int k = 0; k < CPT; ++k) {
            if (scanmask & (1 << k)) {
                const int col = t * CPT + k;
                const float dv = minVal - spc[k];
                v[k] -= dv;
                const int r = row4col[col];
                if (r >= 0) u[r] += dv;
            }
        }
        if (t == 0) u[i] += minVal;

        // augment alternating path (serial, short)
        if (t == 0) {
            int jj = sink;
            while (true) {
                const int ii = path[jj];
                row4col[jj] = ii;
                const int tmp = col4row[ii];
                col4row[ii] = jj;
                jj = tmp;
                if (ii == i) break;
            }
        }
        __syncthreads();  // single wave: cheap
    }

    // gather matched costs (4 rows per thread) and wave-reduce in f64
    double s = 0.0;
    #pragma unroll
    for (int k = 0; k < CPT; ++k) {
        const int row = t * CPT + k;
        const int c = col4row[row];
        s += (double)cost[(size_t)row * N_DIM + c];
    }
    #pragma unroll
    for (int off = 32; off > 0; off >>= 1) s += __shfl_down(s, off);
    if (t == 0) batch_sums[b] = s;
}

__global__ void finalize_kernel(const double* __restrict__ batch_sums,
                                float* __restrict__ out) {
    const int t = threadIdx.x;  // 64 threads, one wave
    double s = batch_sums[t];
    #pragma unroll
    for (int off = 32; off > 0; off >>= 1) s += __shfl_down(s, off);
    if (t == 0) out[0] = (float)(s / (double)((long long)BATCH * N_DIM));
}

extern "C" void kernel_launch(void* const* d_in, const int* in_sizes, int n_in,
                              void* d_out, int out_size, void* d_ws, size_t ws_size,
                              hipStream_t stream) {
    const float* Dm = (const float*)d_in[0];
    float* out = (float*)d_out;
    double* sums = (double*)d_ws;  // 64 * 8 = 512 bytes

    lap_kernel<<<BATCH, BS, 0, stream>>>(Dm, sums);
    finalize_kernel<<<1, 64, 0, stream>>>(sums, out);
}